// Round 2
// baseline (2045.338 us; speedup 1.0000x reference)
//
#include <hip/hip_runtime.h>

// Problem constants (from reference)
#define NB   32768
#define NT   200
#define DE   6
#define NIV  8
#define MH   16
#define NH   128
#define DTC  0.01f

// LDS row layout per hidden unit j (stride LSTR floats):
//  [0..13]  = W1[j][0..13]           (the only columns used by fwd x-part and bwd)
//  [14]     = alpha_j = b1[j] + bE.W1[j][14:30] + bnu.W1[j][30:46]
//  [15]     = beta_j  = WE . W1[j][14:30]    (coefficient of E)
//  [16]     = gamma_j = Wnu . W1[j][30:46]   (coefficient of nu)
//  [17]     = 2 * sum_k W2[k][j]
// stride 20 keeps the 4 sub-lanes' rows in disjoint LDS bank groups.
#define LSTR 20

__global__ __launch_bounds__(256, 2)
void visco_fused(const float* __restrict__ e, const float* __restrict__ edot,
                 const float* __restrict__ Ein, const float* __restrict__ nuin,
                 const float* __restrict__ We1, const float* __restrict__ be1,
                 const float* __restrict__ We2,
                 const float* __restrict__ Wd1, const float* __restrict__ bd1,
                 const float* __restrict__ Wd2,
                 const float* __restrict__ WE,  const float* __restrict__ bE,
                 const float* __restrict__ Wnu, const float* __restrict__ bnu,
                 float* __restrict__ out_stress, float* __restrict__ out_xi)
{
    __shared__ float LE[NH * LSTR];
    __shared__ float LD[NH * LSTR];

    const int tid = threadIdx.x;

    // ---- per-block weight-table build (tiny; threads 0..127, one j each) ----
    if (tid < NH) {
        const int j = tid;
        {
            const float* row = We1 + j * 46;
            float alpha = be1[j], beta = 0.f, gamma = 0.f;
            #pragma unroll
            for (int k = 0; k < MH; ++k) {
                alpha += bE[k]  * row[14 + k] + bnu[k] * row[30 + k];
                beta  += WE[k]  * row[14 + k];
                gamma += Wnu[k] * row[30 + k];
            }
            #pragma unroll
            for (int i = 0; i < 14; ++i) LE[j * LSTR + i] = row[i];
            LE[j * LSTR + 14] = alpha;
            LE[j * LSTR + 15] = beta;
            LE[j * LSTR + 16] = gamma;
            LE[j * LSTR + 17] = 2.0f * (We2[j] + We2[NH + j]);
        }
        {
            const float* row = Wd1 + j * 46;
            float alpha = bd1[j], beta = 0.f, gamma = 0.f;
            #pragma unroll
            for (int k = 0; k < MH; ++k) {
                alpha += bE[k]  * row[14 + k] + bnu[k] * row[30 + k];
                beta  += WE[k]  * row[14 + k];
                gamma += Wnu[k] * row[30 + k];
            }
            #pragma unroll
            for (int i = 0; i < 14; ++i) LD[j * LSTR + i] = row[i];
            LD[j * LSTR + 14] = alpha;
            LD[j * LSTR + 15] = beta;
            LD[j * LSTR + 16] = gamma;
            LD[j * LSTR + 17] = 2.0f * Wd2[j];
        }
    }
    __syncthreads();

    // ---- 4 threads per batch element; sub-lane s owns j = 4*jj + s ----
    const int gt   = blockIdx.x * 256 + tid;
    const int elem = gt >> 2;
    const int s    = tid & 3;

    const float Ev  = Ein[elem];
    const float nuv = nuin[elem];

    float xi[NIV];
    #pragma unroll
    for (int i = 0; i < NIV; ++i) xi[i] = 0.f;

    const float* ep = e    + (size_t)elem * (NT * DE);
    const float* dp = edot + (size_t)elem * (NT * DE);
    float* sp = out_stress + (size_t)elem * (NT * DE);
    float* xp = out_xi     + (size_t)elem * (NT * NIV);

    // software-prefetched strain inputs (cur holds step t, nxt loads t+1)
    float2 ea = *(const float2*)(ep + 0);
    float2 eb = *(const float2*)(ep + 2);
    float2 ec = *(const float2*)(ep + 4);
    float2 da = *(const float2*)(dp + 0);
    float2 db = *(const float2*)(dp + 2);
    float2 dc = *(const float2*)(dp + 4);

    #pragma unroll 1
    for (int t = 0; t < NT; ++t) {
        const int tn = (t + 1 < NT) ? (t + 1) : t;   // clamped prefetch index
        float2 na = *(const float2*)(ep + tn * DE + 0);
        float2 nb = *(const float2*)(ep + tn * DE + 2);
        float2 nc = *(const float2*)(ep + tn * DE + 4);
        float2 ma = *(const float2*)(dp + tn * DE + 0);
        float2 mb = *(const float2*)(dp + tn * DE + 2);
        float2 mc = *(const float2*)(dp + tn * DE + 4);

        // ================= MLP-e gradient: ge[0..13] =================
        float g[14];
        #pragma unroll
        for (int i = 0; i < 14; ++i) g[i] = 0.f;

        #pragma unroll 2
        for (int jj = 0; jj < 32; ++jj) {
            const float* row = &LE[(4 * jj + s) * LSTR];
            float h = fmaf(Ev, row[15], row[14]);
            h = fmaf(nuv,  row[16], h);
            h = fmaf(ea.x, row[0],  h);
            h = fmaf(ea.y, row[1],  h);
            h = fmaf(eb.x, row[2],  h);
            h = fmaf(eb.y, row[3],  h);
            h = fmaf(ec.x, row[4],  h);
            h = fmaf(ec.y, row[5],  h);
            h = fmaf(xi[0], row[6],  h);
            h = fmaf(xi[1], row[7],  h);
            h = fmaf(xi[2], row[8],  h);
            h = fmaf(xi[3], row[9],  h);
            h = fmaf(xi[4], row[10], h);
            h = fmaf(xi[5], row[11], h);
            h = fmaf(xi[6], row[12], h);
            h = fmaf(xi[7], row[13], h);
            const float a = fmaxf(h, 0.f) * row[17];
            #pragma unroll
            for (int i = 0; i < 14; ++i) g[i] = fmaf(a, row[i], g[i]);
        }
        // reduce partial gradients across the 4 sub-lanes (groups are lane-aligned)
        #pragma unroll
        for (int i = 0; i < 14; ++i) {
            g[i] += __shfl_xor(g[i], 1);
            g[i] += __shfl_xor(g[i], 2);
        }
        // s_eq = g[0..5], d = g[6..13]

        // ================= MLP-d gradient: gd[0..13], input [edot, -d, m] =================
        float q[14];
        #pragma unroll
        for (int i = 0; i < 14; ++i) q[i] = 0.f;

        #pragma unroll 2
        for (int jj = 0; jj < 32; ++jj) {
            const float* row = &LD[(4 * jj + s) * LSTR];
            float h = fmaf(Ev, row[15], row[14]);
            h = fmaf(nuv,  row[16], h);
            h = fmaf(da.x, row[0],  h);
            h = fmaf(da.y, row[1],  h);
            h = fmaf(db.x, row[2],  h);
            h = fmaf(db.y, row[3],  h);
            h = fmaf(dc.x, row[4],  h);
            h = fmaf(dc.y, row[5],  h);
            h = fmaf(-g[6],  row[6],  h);
            h = fmaf(-g[7],  row[7],  h);
            h = fmaf(-g[8],  row[8],  h);
            h = fmaf(-g[9],  row[9],  h);
            h = fmaf(-g[10], row[10], h);
            h = fmaf(-g[11], row[11], h);
            h = fmaf(-g[12], row[12], h);
            h = fmaf(-g[13], row[13], h);
            const float a = fmaxf(h, 0.f) * row[17];
            #pragma unroll
            for (int i = 0; i < 14; ++i) q[i] = fmaf(a, row[i], q[i]);
        }
        #pragma unroll
        for (int i = 0; i < 14; ++i) {
            q[i] += __shfl_xor(q[i], 1);
            q[i] += __shfl_xor(q[i], 2);
        }
        // s_neq = q[0..5], kinetics = q[6..13]

        // ================= outputs (xi written PRE-update) =================
        if (s == 0) {
            float2* o = (float2*)(sp + t * DE);
            o[0] = make_float2(g[0] - q[0], g[1] - q[1]);
            o[1] = make_float2(g[2] - q[2], g[3] - q[3]);
            o[2] = make_float2(g[4] - q[4], g[5] - q[5]);
        } else if (s == 1) {
            *(float4*)(xp + t * NIV)     = make_float4(xi[0], xi[1], xi[2], xi[3]);
        } else if (s == 2) {
            *(float4*)(xp + t * NIV + 4) = make_float4(xi[4], xi[5], xi[6], xi[7]);
        }

        #pragma unroll
        for (int i = 0; i < NIV; ++i) xi[i] = fmaf(DTC, q[6 + i], xi[i]);

        ea = na; eb = nb; ec = nc;
        da = ma; db = mb; dc = mc;
    }
}

extern "C" void kernel_launch(void* const* d_in, const int* in_sizes, int n_in,
                              void* d_out, int out_size, void* d_ws, size_t ws_size,
                              hipStream_t stream) {
    const float* e    = (const float*)d_in[0];
    const float* edot = (const float*)d_in[1];
    const float* E    = (const float*)d_in[2];
    const float* nu   = (const float*)d_in[3];
    const float* We1  = (const float*)d_in[4];
    const float* be1  = (const float*)d_in[5];
    const float* We2  = (const float*)d_in[6];
    /* d_in[7] = be2 (unused by the gradient formula) */
    const float* Wd1  = (const float*)d_in[8];
    const float* bd1  = (const float*)d_in[9];
    const float* Wd2  = (const float*)d_in[10];
    /* d_in[11] = bd2 (unused) */
    const float* WE   = (const float*)d_in[12];
    const float* bE   = (const float*)d_in[13];
    const float* Wnu  = (const float*)d_in[14];
    const float* bnu  = (const float*)d_in[15];

    float* out_stress = (float*)d_out;
    float* out_xi     = out_stress + (size_t)NB * NT * DE;

    const int threads = NB * 4;              // 4 threads per batch element
    dim3 grid(threads / 256), block(256);
    visco_fused<<<grid, block, 0, stream>>>(e, edot, E, nu, We1, be1, We2,
                                            Wd1, bd1, Wd2, WE, bE, Wnu, bnu,
                                            out_stress, out_xi);
}